// Round 8
// baseline (791.594 us; speedup 1.0000x reference)
//
#include <hip/hip_runtime.h>
#include <cstdint>
#include <cstddef>

#define HD 128
#define NEG_SLOPE 0.2f
#define BN_EPS 1e-5f

typedef __bf16 bf16x8 __attribute__((ext_vector_type(8)));
typedef float  f32x4  __attribute__((ext_vector_type(4)));

__device__ __forceinline__ unsigned short f2b(float f) {   // fp32 -> bf16 RNE
    unsigned int u = __float_as_uint(f);
    u = (u + 0x7fffu + ((u >> 16) & 1u)) >> 16;
    return (unsigned short)u;
}
__device__ __forceinline__ unsigned int pack2(float lo, float hi) {
    return (unsigned int)f2b(lo) | ((unsigned int)f2b(hi) << 16);
}

// async global->LDS, 16B per lane; LDS dest = wave-uniform base + lane*16
__device__ __forceinline__ void gload_lds16(const void* g, void* l) {
    __builtin_amdgcn_global_load_lds(
        (const __attribute__((address_space(1))) uint32_t*)g,
        (__attribute__((address_space(3))) uint32_t*)l, 16, 0, 0);
}

// =============================================================================
// Weight prep: gw,fw fp32 [K][128] -> Wt bf16 [256][K]  (cols 0..127 = gw,
// 128..255 = fw; cast + transpose, tiny)
// =============================================================================
__global__ void prep_w2(const float* __restrict__ gw, const float* __restrict__ fw,
                        unsigned short* __restrict__ Wt, int K)
{
    int t = blockIdx.x * 256 + threadIdx.x;
    if (t >= K * 256) return;
    int k = t >> 8, c = t & 255;
    float v = (c < 128) ? gw[(size_t)k * 128 + c] : fw[(size_t)k * 128 + (c - 128)];
    Wt[(size_t)c * K + k] = f2b(v);
}

// =============================================================================
// Fused dual GEMM + attention logits: [h|y][M,256] = X[M,K]@Wt[256,K],
// als/ald[M,4] = h . a_src/a_dst  (FUSED into epilogue -- R8: kills the
// 3 al_kernel dispatches + 3x23MB h re-reads; computed from fp32 acc, i.e.
// closer to the fp32 reference than the old bf16-h path).
// GEMM schedule = R7 best (T4 counted vmcnt, 100-112us): gload_lds dbuf,
// raw s_barrier, s_waitcnt vmcnt(4) -- next tile's 4 loads/wave stay in
// flight across both barriers; vmcnt drains to 0 only in prologue/tail.
// Tile 128(M) x 256(N), BK=32, 512 thr = 8 waves (2M x 4N), LDS 2x32KB.
// Both-sides XOR swizzles (write via inverse-swizzled GLOBAL src, rule #21):
//   A fp32 [128][128B]: LDS[r][b]=X[r][b^((r&7)<<4)]   -> 2-way read (free)
//   B bf16 [256][64B]:  LDS[r][b]=Wt[r][b^(((r>>1)&3)<<4)] -> b128 floor
// Frag layouts (verified): A[m=lane&15][k=q*8+j], B[k=q*8+j][n=lane&15],
// D col=lane&15, row=q*4+reg. h cols (wn<2)->bf16 + al butterfly;
// y cols (wn>=2)->fp32 relu((acc+fb)*g+fbeta)+gb.
// al fusion math (wave wn covers heads hA=2wn [ct 0,1], hB=2wn+1 [ct 2,3]):
//   per (rt,r): partial = acc[rt][0]*a[h,m] + acc[rt][1]*a[h,16+m]; butterfly
//   shfl_xor 1/2/4/8 over the 16-lane m-group (q preserved); lane m==0 stores.
// =============================================================================
#define WAITV4 asm volatile("s_waitcnt vmcnt(4)" ::: "memory");
#define WAITV0 asm volatile("s_waitcnt vmcnt(0)" ::: "memory");
#define BAR    __builtin_amdgcn_s_barrier();

#define STAGE(BUF, KOFF)                                                      \
    _Pragma("unroll") for (int i = 0; i < 2; i++)                             \
        gload_lds16(ap[i] + (KOFF), (BUF) + (w + i * 8) * 1024);              \
    _Pragma("unroll") for (int i = 0; i < 2; i++)                             \
        gload_lds16(bp[i] + (KOFF), (BUF) + 16384 + (w + i * 8) * 1024);

#define COMPUTE(BUF)                                                          \
    {                                                                         \
        bf16x8 af[4], bfr[4];                                                 \
        _Pragma("unroll") for (int rt = 0; rt < 4; rt++) {                    \
            int arow = 64 * wm + rt * 16 + m;                                 \
            const char* base = (BUF) + (arow << 7);                           \
            int sw = (m & 7) << 4;                                            \
            f32x4 a0 = *(const f32x4*)(base + ((q * 32)      ^ sw));          \
            f32x4 a1 = *(const f32x4*)(base + ((q * 32 + 16) ^ sw));          \
            uint4 av;                                                         \
            av.x = pack2(a0.x, a0.y); av.y = pack2(a0.z, a0.w);               \
            av.z = pack2(a1.x, a1.y); av.w = pack2(a1.z, a1.w);               \
            af[rt] = *(bf16x8*)&av;                                           \
        }                                                                     \
        _Pragma("unroll") for (int ct = 0; ct < 4; ct++) {                    \
            int brow = 64 * wn + ct * 16 + m;                                 \
            bfr[ct] = *(const bf16x8*)((BUF) + 16384 + (brow << 6) +          \
                                       ((q * 16) ^ (((m >> 1) & 3) << 4)));   \
        }                                                                     \
        _Pragma("unroll") for (int rt = 0; rt < 4; rt++)                      \
            _Pragma("unroll") for (int ct = 0; ct < 4; ct++)                  \
                acc[rt][ct] = __builtin_amdgcn_mfma_f32_16x16x32_bf16(        \
                    af[rt], bfr[ct], acc[rt][ct], 0, 0, 0);                   \
    }

__global__ __launch_bounds__(512, 4) void gemm_dual(
    const float* __restrict__ X, const unsigned short* __restrict__ Wt,
    unsigned short* __restrict__ hb, float* __restrict__ yb, int M, int K,
    const float* __restrict__ fb, const float* __restrict__ fg,
    const float* __restrict__ fbeta, const float* __restrict__ gb,
    const float* __restrict__ a_src, const float* __restrict__ a_dst,
    float* __restrict__ als, float* __restrict__ ald)
{
    __shared__ __align__(16) char smem[2 * 32768];   // [buf][A 16K | B 16K]
    char* buf0 = smem;
    char* buf1 = smem + 32768;

    const int tid  = threadIdx.x;
    const int row0 = blockIdx.x * 128;
    const int w    = tid >> 6, lane = tid & 63;
    const int wm   = w & 1,  wn = w >> 1;
    const int m    = lane & 15, q = lane >> 4;

    // ---- staging source addresses (inverse-swizzled per lane) ----
    const int la = lane >> 3, ca = lane & 7;     // A: chunk row la, 16B col ca
    const int lb = lane >> 2, cb = lane & 3;     // B: chunk row lb, 16B col cb
    const int oA = 4 * (ca ^ la);                // float offset in 32-f slice
    const int oB = 8 * (cb ^ (la & 3));          // short offset in 32-s slice

    const float* ap[2];
    const unsigned short* bp[2];
#pragma unroll
    for (int i = 0; i < 2; i++) {
        int ch = w + i * 8;                      // A chunk 0..15 (8 rows each)
        int gr = row0 + ch * 8 + la; if (gr >= M) gr = M - 1;
        ap[i] = X + (size_t)gr * K + oA;
        int rB = ch * 16 + lb;                   // B row 0..255 (= out col)
        bp[i] = Wt + (size_t)rB * K + oB;
    }

    f32x4 acc[4][4];
#pragma unroll
    for (int rt = 0; rt < 4; rt++)
#pragma unroll
        for (int ct = 0; ct < 4; ct++) acc[rt][ct] = (f32x4){0.f, 0.f, 0.f, 0.f};

    STAGE(buf0, 0)
    for (int ks = 0; ks < K; ks += 64) {         // K % 64 == 0 (512 or 128)
        STAGE(buf1, ks + 32)
        WAITV4
        BAR
        COMPUTE(buf0)
        BAR
        if (ks + 64 < K) { STAGE(buf0, ks + 64) WAITV4 } else { WAITV0 }
        BAR
        COMPUTE(buf1)
        BAR
    }

    // epilogue: D[row = row0+64*wm+rt*16+q*4+r][gcol = 64*wn+ct*16+m]
    const bool full = (row0 + 128 <= M);
    if (wn < 2) {              // h half, bf16 + fused attention logits
#pragma unroll
        for (int ct = 0; ct < 4; ct++) {
            int col = 64 * wn + ct * 16 + m;
#pragma unroll
            for (int rt = 0; rt < 4; rt++)
#pragma unroll
                for (int r = 0; r < 4; r++) {
                    int row = row0 + 64 * wm + rt * 16 + q * 4 + r;
                    if (full || row < M) hb[(size_t)row * HD + col] = f2b(acc[rt][ct][r]);
                }
        }
        // ---- fused al: heads hA=2wn (ct 0,1), hB=2wn+1 (ct 2,3) ----
        const int hA = 2 * wn, hB2 = 2 * wn + 1;
        const float asA0 = a_src[hA * 32 + m],  asA1 = a_src[hA * 32 + 16 + m];
        const float asB0 = a_src[hB2 * 32 + m], asB1 = a_src[hB2 * 32 + 16 + m];
        const float adA0 = a_dst[hA * 32 + m],  adA1 = a_dst[hA * 32 + 16 + m];
        const float adB0 = a_dst[hB2 * 32 + m], adB1 = a_dst[hB2 * 32 + 16 + m];
#pragma unroll
        for (int rt = 0; rt < 4; rt++)
#pragma unroll
            for (int r = 0; r < 4; r++) {
                int row = row0 + 64 * wm + rt * 16 + q * 4 + r;
                float sA = acc[rt][0][r] * asA0 + acc[rt][1][r] * asA1;
                float sB = acc[rt][2][r] * asB0 + acc[rt][3][r] * asB1;
                float dA = acc[rt][0][r] * adA0 + acc[rt][1][r] * adA1;
                float dB = acc[rt][2][r] * adB0 + acc[rt][3][r] * adB1;
#pragma unroll
                for (int off = 1; off < 16; off <<= 1) {
                    sA += __shfl_xor(sA, off);
                    sB += __shfl_xor(sB, off);
                    dA += __shfl_xor(dA, off);
                    dB += __shfl_xor(dB, off);
                }
                if (m == 0 && (full || row < M)) {
                    als[row * 4 + hA]  = sA;
                    als[row * 4 + hB2] = sB;
                    ald[row * 4 + hA]  = dA;
                    ald[row * 4 + hB2] = dB;
                }
            }
    } else {                   // y half, fp32 with BN+relu+gb
        const float inv_bn = 1.0f / sqrtf(1.0f + BN_EPS);
#pragma unroll
        for (int ct = 0; ct < 4; ct++) {
            int col = 64 * (wn - 2) + ct * 16 + m;
            float g  = fg[col] * inv_bn;
            float bb = fb[col];
            float bt = fbeta[col];
            float gv = gb[col];
#pragma unroll
            for (int rt = 0; rt < 4; rt++)
#pragma unroll
                for (int r = 0; r < 4; r++) {
                    int row = row0 + 64 * wm + rt * 16 + q * 4 + r;
                    if (full || row < M) {
                        float y = (acc[rt][ct][r] + bb) * g + bt;
                        y = y > 0.f ? y : 0.f;       // feature_transform relu
                        yb[(size_t)row * HD + col] = y + gv;
                    }
                }
        }
    }
}

// ============================ CSR build (once) ===============================
__global__ void hist_kernel(const int* __restrict__ ei, int E, int N, int* __restrict__ deg)
{
    int t = blockIdx.x * blockDim.x + threadIdx.x;
    if (t >= E + N) return;
    int d = (t < E) ? ei[E + t] : (t - E);
    atomicAdd(&deg[d], 1);
}

__global__ void scan1(const int* __restrict__ deg, int* __restrict__ rp,
                      int* __restrict__ bsum, int N)
{
    __shared__ int sh[256];
    int t = threadIdx.x;
    int i0 = blockIdx.x * 1024 + t * 4;
    int v[4];
#pragma unroll
    for (int j = 0; j < 4; j++) v[j] = (i0 + j < N) ? deg[i0 + j] : 0;
    int tot = v[0] + v[1] + v[2] + v[3];
    sh[t] = tot;
    __syncthreads();
    for (int off = 1; off < 256; off <<= 1) {
        int xv = (t >= off) ? sh[t - off] : 0;
        __syncthreads();
        sh[t] += xv;
        __syncthreads();
    }
    int run = sh[t] - tot;
    if (t == 255) bsum[blockIdx.x] = sh[255];
#pragma unroll
    for (int j = 0; j < 4; j++) {
        if (i0 + j < N) rp[i0 + j] = run;
        run += v[j];
    }
}

__global__ void scan2(int* __restrict__ bsum, int nb)
{
    if (threadIdx.x == 0 && blockIdx.x == 0) {
        int run = 0;
        for (int i = 0; i < nb; i++) { int v = bsum[i]; bsum[i] = run; run += v; }
    }
}

__global__ void scan3(int* __restrict__ rp, int* __restrict__ cur,
                      const int* __restrict__ bsum, int N, int Etot)
{
    int t = blockIdx.x * blockDim.x + threadIdx.x;
    if (t < N) {
        int v = rp[t] + bsum[t >> 10];
        rp[t] = v;
        cur[t] = v;
    } else if (t == N) {
        rp[N] = Etot;
    }
}

__global__ void scatter_kernel(const int* __restrict__ ei, int E, int N,
                               int* __restrict__ cur, int* __restrict__ col)
{
    int t = blockIdx.x * blockDim.x + threadIdx.x;
    if (t >= E + N) return;
    int s, d;
    if (t < E) { s = ei[t]; d = ei[E + t]; } else { s = t - E; d = t - E; }
    int p = atomicAdd(&cur[d], 1);
    col[p] = s;
}

// ============================ aggregation ====================================
// SINGLE-PASS per dst (no max-subtraction: logits ~N(0,sqrt2), |e|<~20, exp
// is fp32-safe; softmax value identical). One wave per dst. R8: 8 edge-slots
// x 8 lanes x 32B (2x gather MLP vs 4x16) + 1-deep pipeline of the dependent
// chain col[j] -> als[s]/h[s]. lane=(g=lane>>3 slot, c=lane&7 group of 16ch,
// head=c>>1). Combine slots via shfl_xor(8|16|32). xio fp32 RMW + layer relu.
// Last layer (cw != null): classifier FUSED -- skip the xio store (dead),
// compute out[wid,0..10) = relu_x @ cw + cb via per-lane 16ch partials +
// 3-level butterfly over lanes 0..7; kills cls_kernel + 82MB of traffic.
__global__ __launch_bounds__(256) void agg_kernel(
    const unsigned short* __restrict__ h, const float* __restrict__ als,
    const float* __restrict__ ald, const int* __restrict__ rp,
    const int* __restrict__ col, float* __restrict__ xio, int N,
    const float* __restrict__ cw, const float* __restrict__ cb,
    float* __restrict__ out)
{
    int wid  = (blockIdx.x * blockDim.x + threadIdx.x) >> 6;
    int lane = threadIdx.x & 63;
    if (wid >= N) return;
    int beg = rp[wid], end = rp[wid + 1];

    int g = lane >> 3, c = lane & 7, hB = c >> 1;
    float ad_h = ald[wid * 4 + hB];
    float acc[16];
#pragma unroll
    for (int p = 0; p < 16; p++) acc[p] = 0.f;
    float wsum = 0.f;
    const unsigned short* hbase = h + c * 16;

    int j = beg + g;
    float alc = 0.f;
    uint4 hvc0 = (uint4){0, 0, 0, 0}, hvc1 = (uint4){0, 0, 0, 0};
    if (j < end) {
        int s0 = col[j];
        alc = als[s0 * 4 + hB];
        const uint4* hp = (const uint4*)(hbase + (size_t)s0 * HD);
        hvc0 = hp[0]; hvc1 = hp[1];
    }
    while (j < end) {
        int jn = j + 8;
        float aln = 0.f;
        uint4 hvn0 = (uint4){0, 0, 0, 0}, hvn1 = (uint4){0, 0, 0, 0};
        if (jn < end) {
            int sn = col[jn];                                   // issued early
            aln = als[sn * 4 + hB];
            const uint4* hp = (const uint4*)(hbase + (size_t)sn * HD);
            hvn0 = hp[0]; hvn1 = hp[1];
        }
        float e = alc + ad_h;
        e = e > 0.f ? e : NEG_SLOPE * e;
        float wgt = __expf(e);
        wsum += wgt;
        unsigned int uu[8] = {hvc0.x, hvc0.y, hvc0.z, hvc0.w,
                              hvc1.x, hvc1.y, hvc1.z, hvc1.w};
#pragma unroll
        for (int p = 0; p < 8; p++) {
            acc[2 * p]     += wgt * __uint_as_float(uu[p] << 16);
            acc[2 * p + 1] += wgt * __uint_as_float(uu[p] & 0xffff0000u);
        }
        j = jn; alc = aln; hvc0 = hvn0; hvc1 = hvn1;
    }
#pragma unroll
    for (int p = 0; p < 16; p++) {
        acc[p] += __shfl_xor(acc[p], 8);
        acc[p] += __shfl_xor(acc[p], 16);
        acc[p] += __shfl_xor(acc[p], 32);
    }
    wsum += __shfl_xor(wsum, 8);
    wsum += __shfl_xor(wsum, 16);
    wsum += __shfl_xor(wsum, 32);
    if (g == 0) {                                // lanes 0..7, c = lane
        float inv = 1.0f / wsum;
        float* xp = xio + (size_t)wid * HD + c * 16;
        float xv[16];
#pragma unroll
        for (int b = 0; b < 4; b++)
            *(float4*)(xv + 4 * b) = *(const float4*)(xp + 4 * b);
        float o_[16];
#pragma unroll
        for (int p = 0; p < 16; p++) {
            float t = acc[p] * inv + xv[p];
            o_[p] = t > 0.f ? t : 0.f;           // layer relu
        }
        if (cw == nullptr) {
#pragma unroll
            for (int b = 0; b < 4; b++)
                *(float4*)(xp + 4 * b) = *(const float4*)(o_ + 4 * b);
        } else {
            // fused classifier: out[wid,o] = sum_c x[c]*cw[c*10+o] + cb[o]
            float po[10];
#pragma unroll
            for (int o = 0; o < 10; o++) {
                float s = 0.f;
#pragma unroll
                for (int p = 0; p < 16; p++)
                    s += o_[p] * cw[(c * 16 + p) * 10 + o];
                po[o] = s;
            }
#pragma unroll
            for (int o = 0; o < 10; o++) {
                po[o] += __shfl_xor(po[o], 1);
                po[o] += __shfl_xor(po[o], 2);
                po[o] += __shfl_xor(po[o], 4);
            }
            if (c == 0) {
#pragma unroll
                for (int o = 0; o < 10; o++)
                    out[(size_t)wid * 10 + o] = po[o] + cb[o];
            }
        }
    }
}

// =============================================================================
extern "C" void kernel_launch(void* const* d_in, const int* in_sizes, int n_in,
                              void* d_out, int out_size, void* d_ws, size_t ws_size,
                              hipStream_t stream)
{
    const float* x0 = (const float*)d_in[0];
    const int*   ei = (const int*)d_in[1];
    const int N = in_sizes[0] / 512;
    const int E = in_sizes[1] / 2;
    const int Etot = E + N;

    const float *gw[3], *gas[3], *gad[3], *gbp[3], *fw[3], *fbp[3], *fgp[3], *fbt[3];
    for (int l = 0; l < 3; l++) {
        int b = 3 + 8 * l;
        gw[l]  = (const float*)d_in[b + 0];
        gas[l] = (const float*)d_in[b + 1];
        gad[l] = (const float*)d_in[b + 2];
        gbp[l] = (const float*)d_in[b + 3];
        fw[l]  = (const float*)d_in[b + 4];
        fbp[l] = (const float*)d_in[b + 5];
        fgp[l] = (const float*)d_in[b + 6];
        fbt[l] = (const float*)d_in[b + 7];
    }
    const float* cw = (const float*)d_in[27];
    const float* cb = (const float*)d_in[28];

    char* p = (char*)d_ws;
    auto carve = [&](size_t bytes) -> char* {
        char* r = p; p += (bytes + 255) & ~(size_t)255; return r;
    };
    float* xA   = (float*)carve((size_t)N * HD * 4);
    float* xB   = (float*)carve((size_t)N * HD * 4);
    unsigned short* hbuf = (unsigned short*)carve((size_t)N * HD * 2);   // bf16 h
    float* als  = (float*)carve((size_t)N * 4 * 4);
    float* ald  = (float*)carve((size_t)N * 4 * 4);
    int* rp   = (int*)carve((size_t)(N + 1) * 4);
    int* deg  = (int*)carve((size_t)N * 4);
    int* cur  = (int*)carve((size_t)N * 4);
    int* bsum = (int*)carve(4096);
    int* col  = (int*)carve((size_t)Etot * 4);
    unsigned short* wT[3];
    for (int l = 0; l < 3; l++) {
        int K = (l == 0) ? 512 : HD;
        wT[l] = (unsigned short*)carve((size_t)256 * K * 2);
    }

    // ---- weight cast+transpose+concat (tiny) ----
    for (int l = 0; l < 3; l++) {
        int K = (l == 0) ? 512 : HD;
        int nt = K * 256;
        prep_w2<<<(nt + 255) / 256, 256, 0, stream>>>(gw[l], fw[l], wT[l], K);
    }

    // ---- CSR by dst ----
    hipMemsetAsync(deg, 0, (size_t)N * 4, stream);
    hist_kernel<<<(Etot + 255) / 256, 256, 0, stream>>>(ei, E, N, deg);
    int nb = (N + 1023) / 1024;
    scan1<<<nb, 256, 0, stream>>>(deg, rp, bsum, N);
    scan2<<<1, 64, 0, stream>>>(bsum, nb);
    scan3<<<(N + 256) / 256, 256, 0, stream>>>(rp, cur, bsum, N, Etot);
    scatter_kernel<<<(Etot + 255) / 256, 256, 0, stream>>>(ei, E, N, cur, col);

    // ---- 3 message-passing layers (al fused into gemm; cls fused into
    //      last agg) ----
    for (int l = 0; l < 3; l++) {
        const float* xin = (l == 0) ? x0 : ((l == 1) ? xA : xB);
        float* xout = (l == 1) ? xB : xA;
        int K = (l == 0) ? 512 : HD;
        int mblocks = (N + 127) / 128;
        gemm_dual<<<mblocks, 512, 0, stream>>>(xin, wT[l], hbuf, xout, N, K,
                                               fbp[l], fgp[l], fbt[l], gbp[l],
                                               gas[l], gad[l], als, ald);
        agg_kernel<<<(N + 3) / 4, 256, 0, stream>>>(
            hbuf, als, ald, rp, col, xout, N,
            (l == 2) ? cw : nullptr, cb, (float*)d_out);
    }
}

// Round 9
// 732.235 us; speedup vs baseline: 1.0811x; 1.0811x over previous
//
#include <hip/hip_runtime.h>
#include <cstdint>
#include <cstddef>

#define HD 128
#define NEG_SLOPE 0.2f
#define BN_EPS 1e-5f

typedef __bf16 bf16x8 __attribute__((ext_vector_type(8)));
typedef float  f32x4  __attribute__((ext_vector_type(4)));

__device__ __forceinline__ unsigned short f2b(float f) {   // fp32 -> bf16 RNE
    unsigned int u = __float_as_uint(f);
    u = (u + 0x7fffu + ((u >> 16) & 1u)) >> 16;
    return (unsigned short)u;
}
__device__ __forceinline__ unsigned int pack2(float lo, float hi) {
    return (unsigned int)f2b(lo) | ((unsigned int)f2b(hi) << 16);
}

// async global->LDS, 16B per lane; LDS dest = wave-uniform base + lane*16
__device__ __forceinline__ void gload_lds16(const void* g, void* l) {
    __builtin_amdgcn_global_load_lds(
        (const __attribute__((address_space(1))) uint32_t*)g,
        (__attribute__((address_space(3))) uint32_t*)l, 16, 0, 0);
}

// =============================================================================
// Weight prep: gw,fw fp32 [K][128] -> Wt bf16 [256][K]  (cols 0..127 = gw,
// 128..255 = fw; cast + transpose, tiny)
// =============================================================================
__global__ void prep_w2(const float* __restrict__ gw, const float* __restrict__ fw,
                        unsigned short* __restrict__ Wt, int K)
{
    int t = blockIdx.x * 256 + threadIdx.x;
    if (t >= K * 256) return;
    int k = t >> 8, c = t & 255;
    float v = (c < 128) ? gw[(size_t)k * 128 + c] : fw[(size_t)k * 128 + (c - 128)];
    Wt[(size_t)c * K + k] = f2b(v);
}

// =============================================================================
// Fused dual GEMM + attention logits (unchanged from R8, verified):
// [h|y][M,256] = X[M,K]@Wt[256,K]; als/ald[M,4] = h . a_src/a_dst fused in
// the epilogue from fp32 acc. GEMM schedule = R7 best (T4 counted vmcnt):
// gload_lds dbuf, raw s_barrier, s_waitcnt vmcnt(4); vmcnt drains to 0 only
// in prologue/tail. Tile 128x256, BK=32, 512 thr = 8 waves (2M x 4N),
// LDS 2x32KB. Both-sides XOR swizzles (rule #21):
//   A fp32 [128][128B]: LDS[r][b]=X[r][b^((r&7)<<4)]
//   B bf16 [256][64B]:  LDS[r][b]=Wt[r][b^(((r>>1)&3)<<4)]
// Frag layouts (verified): A[m=lane&15][k=q*8+j], B[k=q*8+j][n=lane&15],
// D col=lane&15, row=q*4+reg. h cols (wn<2)->bf16 + al butterfly;
// y cols (wn>=2)->fp32 relu((acc+fb)*g+fbeta)+gb.
// =============================================================================
#define WAITV4 asm volatile("s_waitcnt vmcnt(4)" ::: "memory");
#define WAITV0 asm volatile("s_waitcnt vmcnt(0)" ::: "memory");
#define BAR    __builtin_amdgcn_s_barrier();

#define STAGE(BUF, KOFF)                                                      \
    _Pragma("unroll") for (int i = 0; i < 2; i++)                             \
        gload_lds16(ap[i] + (KOFF), (BUF) + (w + i * 8) * 1024);              \
    _Pragma("unroll") for (int i = 0; i < 2; i++)                             \
        gload_lds16(bp[i] + (KOFF), (BUF) + 16384 + (w + i * 8) * 1024);

#define COMPUTE(BUF)                                                          \
    {                                                                         \
        bf16x8 af[4], bfr[4];                                                 \
        _Pragma("unroll") for (int rt = 0; rt < 4; rt++) {                    \
            int arow = 64 * wm + rt * 16 + m;                                 \
            const char* base = (BUF) + (arow << 7);                           \
            int sw = (m & 7) << 4;                                            \
            f32x4 a0 = *(const f32x4*)(base + ((q * 32)      ^ sw));          \
            f32x4 a1 = *(const f32x4*)(base + ((q * 32 + 16) ^ sw));          \
            uint4 av;                                                         \
            av.x = pack2(a0.x, a0.y); av.y = pack2(a0.z, a0.w);               \
            av.z = pack2(a1.x, a1.y); av.w = pack2(a1.z, a1.w);               \
            af[rt] = *(bf16x8*)&av;                                           \
        }                                                                     \
        _Pragma("unroll") for (int ct = 0; ct < 4; ct++) {                    \
            int brow = 64 * wn + ct * 16 + m;                                 \
            bfr[ct] = *(const bf16x8*)((BUF) + 16384 + (brow << 6) +          \
                                       ((q * 16) ^ (((m >> 1) & 3) << 4)));   \
        }                                                                     \
        _Pragma("unroll") for (int rt = 0; rt < 4; rt++)                      \
            _Pragma("unroll") for (int ct = 0; ct < 4; ct++)                  \
                acc[rt][ct] = __builtin_amdgcn_mfma_f32_16x16x32_bf16(        \
                    af[rt], bfr[ct], acc[rt][ct], 0, 0, 0);                   \
    }

__global__ __launch_bounds__(512, 4) void gemm_dual(
    const float* __restrict__ X, const unsigned short* __restrict__ Wt,
    unsigned short* __restrict__ hb, float* __restrict__ yb, int M, int K,
    const float* __restrict__ fb, const float* __restrict__ fg,
    const float* __restrict__ fbeta, const float* __restrict__ gb,
    const float* __restrict__ a_src, const float* __restrict__ a_dst,
    float* __restrict__ als, float* __restrict__ ald)
{
    __shared__ __align__(16) char smem[2 * 32768];   // [buf][A 16K | B 16K]
    char* buf0 = smem;
    char* buf1 = smem + 32768;

    const int tid  = threadIdx.x;
    const int row0 = blockIdx.x * 128;
    const int w    = tid >> 6, lane = tid & 63;
    const int wm   = w & 1,  wn = w >> 1;
    const int m    = lane & 15, q = lane >> 4;

    // ---- staging source addresses (inverse-swizzled per lane) ----
    const int la = lane >> 3, ca = lane & 7;     // A: chunk row la, 16B col ca
    const int lb = lane >> 2, cb = lane & 3;     // B: chunk row lb, 16B col cb
    const int oA = 4 * (ca ^ la);                // float offset in 32-f slice
    const int oB = 8 * (cb ^ (la & 3));          // short offset in 32-s slice

    const float* ap[2];
    const unsigned short* bp[2];
#pragma unroll
    for (int i = 0; i < 2; i++) {
        int ch = w + i * 8;                      // A chunk 0..15 (8 rows each)
        int gr = row0 + ch * 8 + la; if (gr >= M) gr = M - 1;
        ap[i] = X + (size_t)gr * K + oA;
        int rB = ch * 16 + lb;                   // B row 0..255 (= out col)
        bp[i] = Wt + (size_t)rB * K + oB;
    }

    f32x4 acc[4][4];
#pragma unroll
    for (int rt = 0; rt < 4; rt++)
#pragma unroll
        for (int ct = 0; ct < 4; ct++) acc[rt][ct] = (f32x4){0.f, 0.f, 0.f, 0.f};

    STAGE(buf0, 0)
    for (int ks = 0; ks < K; ks += 64) {         // K % 64 == 0 (512 or 128)
        STAGE(buf1, ks + 32)
        WAITV4
        BAR
        COMPUTE(buf0)
        BAR
        if (ks + 64 < K) { STAGE(buf0, ks + 64) WAITV4 } else { WAITV0 }
        BAR
        COMPUTE(buf1)
        BAR
    }

    // epilogue: D[row = row0+64*wm+rt*16+q*4+r][gcol = 64*wn+ct*16+m]
    const bool full = (row0 + 128 <= M);
    if (wn < 2) {              // h half, bf16 + fused attention logits
#pragma unroll
        for (int ct = 0; ct < 4; ct++) {
            int col = 64 * wn + ct * 16 + m;
#pragma unroll
            for (int rt = 0; rt < 4; rt++)
#pragma unroll
                for (int r = 0; r < 4; r++) {
                    int row = row0 + 64 * wm + rt * 16 + q * 4 + r;
                    if (full || row < M) hb[(size_t)row * HD + col] = f2b(acc[rt][ct][r]);
                }
        }
        // ---- fused al: heads hA=2wn (ct 0,1), hB=2wn+1 (ct 2,3) ----
        const int hA = 2 * wn, hB2 = 2 * wn + 1;
        const float asA0 = a_src[hA * 32 + m],  asA1 = a_src[hA * 32 + 16 + m];
        const float asB0 = a_src[hB2 * 32 + m], asB1 = a_src[hB2 * 32 + 16 + m];
        const float adA0 = a_dst[hA * 32 + m],  adA1 = a_dst[hA * 32 + 16 + m];
        const float adB0 = a_dst[hB2 * 32 + m], adB1 = a_dst[hB2 * 32 + 16 + m];
#pragma unroll
        for (int rt = 0; rt < 4; rt++)
#pragma unroll
            for (int r = 0; r < 4; r++) {
                int row = row0 + 64 * wm + rt * 16 + q * 4 + r;
                float sA = acc[rt][0][r] * asA0 + acc[rt][1][r] * asA1;
                float sB = acc[rt][2][r] * asB0 + acc[rt][3][r] * asB1;
                float dA = acc[rt][0][r] * adA0 + acc[rt][1][r] * adA1;
                float dB = acc[rt][2][r] * adB0 + acc[rt][3][r] * adB1;
#pragma unroll
                for (int off = 1; off < 16; off <<= 1) {
                    sA += __shfl_xor(sA, off);
                    sB += __shfl_xor(sB, off);
                    dA += __shfl_xor(dA, off);
                    dB += __shfl_xor(dB, off);
                }
                if (m == 0 && (full || row < M)) {
                    als[row * 4 + hA]  = sA;
                    als[row * 4 + hB2] = sB;
                    ald[row * 4 + hA]  = dA;
                    ald[row * 4 + hB2] = dB;
                }
            }
    } else {                   // y half, fp32 with BN+relu+gb
        const float inv_bn = 1.0f / sqrtf(1.0f + BN_EPS);
#pragma unroll
        for (int ct = 0; ct < 4; ct++) {
            int col = 64 * (wn - 2) + ct * 16 + m;
            float g  = fg[col] * inv_bn;
            float bb = fb[col];
            float bt = fbeta[col];
            float gv = gb[col];
#pragma unroll
            for (int rt = 0; rt < 4; rt++)
#pragma unroll
                for (int r = 0; r < 4; r++) {
                    int row = row0 + 64 * wm + rt * 16 + q * 4 + r;
                    if (full || row < M) {
                        float y = (acc[rt][ct][r] + bb) * g + bt;
                        y = y > 0.f ? y : 0.f;       // feature_transform relu
                        yb[(size_t)row * HD + col] = y + gv;
                    }
                }
        }
    }
}

// ============================ CSR build (once) ===============================
__global__ void hist_kernel(const int* __restrict__ ei, int E, int N, int* __restrict__ deg)
{
    int t = blockIdx.x * blockDim.x + threadIdx.x;
    if (t >= E + N) return;
    int d = (t < E) ? ei[E + t] : (t - E);
    atomicAdd(&deg[d], 1);
}

__global__ void scan1(const int* __restrict__ deg, int* __restrict__ rp,
                      int* __restrict__ bsum, int N)
{
    __shared__ int sh[256];
    int t = threadIdx.x;
    int i0 = blockIdx.x * 1024 + t * 4;
    int v[4];
#pragma unroll
    for (int j = 0; j < 4; j++) v[j] = (i0 + j < N) ? deg[i0 + j] : 0;
    int tot = v[0] + v[1] + v[2] + v[3];
    sh[t] = tot;
    __syncthreads();
    for (int off = 1; off < 256; off <<= 1) {
        int xv = (t >= off) ? sh[t - off] : 0;
        __syncthreads();
        sh[t] += xv;
        __syncthreads();
    }
    int run = sh[t] - tot;
    if (t == 255) bsum[blockIdx.x] = sh[255];
#pragma unroll
    for (int j = 0; j < 4; j++) {
        if (i0 + j < N) rp[i0 + j] = run;
        run += v[j];
    }
}

__global__ void scan2(int* __restrict__ bsum, int nb)
{
    if (threadIdx.x == 0 && blockIdx.x == 0) {
        int run = 0;
        for (int i = 0; i < nb; i++) { int v = bsum[i]; bsum[i] = run; run += v; }
    }
}

__global__ void scan3(int* __restrict__ rp, int* __restrict__ cur,
                      const int* __restrict__ bsum, int N, int Etot)
{
    int t = blockIdx.x * blockDim.x + threadIdx.x;
    if (t < N) {
        int v = rp[t] + bsum[t >> 10];
        rp[t] = v;
        cur[t] = v;
    } else if (t == N) {
        rp[N] = Etot;
    }
}

__global__ void scatter_kernel(const int* __restrict__ ei, int E, int N,
                               int* __restrict__ cur, int* __restrict__ col)
{
    int t = blockIdx.x * blockDim.x + threadIdx.x;
    if (t >= E + N) return;
    int s, d;
    if (t < E) { s = ei[t]; d = ei[E + t]; } else { s = t - E; d = t - E; }
    int p = atomicAdd(&cur[d], 1);
    col[p] = s;
}

// ============================ aggregation ====================================
// R9: gather core REVERTED to the proven R7 layout -- 4 edge-slots x 16 lanes
// x 16B (one fully-coalesced 256B h-row read per edge; R8's 8x8x32B doubled
// TCC line-visits per edge -> FETCH 167MB, 160us). 1-deep pipeline of the
// per-lane chain col[j] -> als[s]/h[s]. lane=(g=lane>>4 slot, c=lane&15
// channel-group of 8, head=c>>2). Combine slots via shfl_xor(16|32).
// Single-pass softmax (logits small, exp fp32-safe). xio fp32 RMW + relu.
// Last layer (cw != null): classifier fused on the 16-lane layout -- skip
// the dead xio store; po[o] = sum_{p<8} x[c*8+p]*cw[(c*8+p)*10+o], butterfly
// over 16 lanes, lane 0 writes 10 floats (+cb).
__global__ __launch_bounds__(256) void agg_kernel(
    const unsigned short* __restrict__ h, const float* __restrict__ als,
    const float* __restrict__ ald, const int* __restrict__ rp,
    const int* __restrict__ col, float* __restrict__ xio, int N,
    const float* __restrict__ cw, const float* __restrict__ cb,
    float* __restrict__ out)
{
    int wid  = (blockIdx.x * blockDim.x + threadIdx.x) >> 6;
    int lane = threadIdx.x & 63;
    if (wid >= N) return;
    int beg = rp[wid], end = rp[wid + 1];

    int g = lane >> 4, c = lane & 15, hB = c >> 2;
    float ad_h = ald[wid * 4 + hB];
    float acc[8];
#pragma unroll
    for (int p = 0; p < 8; p++) acc[p] = 0.f;
    float wsum = 0.f;
    const unsigned short* hbase = h + c * 8;

    int j = beg + g;
    float alc = 0.f;
    uint4 hvc = (uint4){0, 0, 0, 0};
    if (j < end) {
        int s0 = col[j];
        alc = als[s0 * 4 + hB];
        hvc = *(const uint4*)(hbase + (size_t)s0 * HD);
    }
    while (j < end) {
        int jn = j + 4;
        float aln = 0.f;
        uint4 hvn = (uint4){0, 0, 0, 0};
        if (jn < end) {
            int sn = col[jn];                                   // issued early
            aln = als[sn * 4 + hB];
            hvn = *(const uint4*)(hbase + (size_t)sn * HD);
        }
        float e = alc + ad_h;
        e = e > 0.f ? e : NEG_SLOPE * e;
        float wgt = __expf(e);
        wsum += wgt;
        unsigned int uu[4] = {hvc.x, hvc.y, hvc.z, hvc.w};
#pragma unroll
        for (int p = 0; p < 4; p++) {
            acc[2 * p]     += wgt * __uint_as_float(uu[p] << 16);
            acc[2 * p + 1] += wgt * __uint_as_float(uu[p] & 0xffff0000u);
        }
        j = jn; alc = aln; hvc = hvn;
    }
#pragma unroll
    for (int p = 0; p < 8; p++) {
        acc[p] += __shfl_xor(acc[p], 16);
        acc[p] += __shfl_xor(acc[p], 32);
    }
    wsum += __shfl_xor(wsum, 16);
    wsum += __shfl_xor(wsum, 32);
    if (g == 0) {                                // lanes 0..15, c = lane
        float inv = 1.0f / wsum;
        float* xp = xio + (size_t)wid * HD + c * 8;
        float4 x0 = *(float4*)xp, x1 = *(float4*)(xp + 4);
        float o_[8] = {acc[0] * inv + x0.x, acc[1] * inv + x0.y,
                       acc[2] * inv + x0.z, acc[3] * inv + x0.w,
                       acc[4] * inv + x1.x, acc[5] * inv + x1.y,
                       acc[6] * inv + x1.z, acc[7] * inv + x1.w};
#pragma unroll
        for (int p = 0; p < 8; p++) o_[p] = o_[p] > 0.f ? o_[p] : 0.f;
        if (cw == nullptr) {
            *(float4*)xp       = (float4){o_[0], o_[1], o_[2], o_[3]};
            *(float4*)(xp + 4) = (float4){o_[4], o_[5], o_[6], o_[7]};
        } else {
            // fused classifier: out[wid,o] = sum_ch x[ch]*cw[ch*10+o] + cb[o]
            float po[10];
#pragma unroll
            for (int o = 0; o < 10; o++) {
                float s = 0.f;
#pragma unroll
                for (int p = 0; p < 8; p++)
                    s += o_[p] * cw[(c * 8 + p) * 10 + o];
                po[o] = s;
            }
#pragma unroll
            for (int o = 0; o < 10; o++) {
                po[o] += __shfl_xor(po[o], 1);
                po[o] += __shfl_xor(po[o], 2);
                po[o] += __shfl_xor(po[o], 4);
                po[o] += __shfl_xor(po[o], 8);
            }
            if (c == 0) {
#pragma unroll
                for (int o = 0; o < 10; o++)
                    out[(size_t)wid * 10 + o] = po[o] + cb[o];
            }
        }
    }
}

// =============================================================================
extern "C" void kernel_launch(void* const* d_in, const int* in_sizes, int n_in,
                              void* d_out, int out_size, void* d_ws, size_t ws_size,
                              hipStream_t stream)
{
    const float* x0 = (const float*)d_in[0];
    const int*   ei = (const int*)d_in[1];
    const int N = in_sizes[0] / 512;
    const int E = in_sizes[1] / 2;
    const int Etot = E + N;

    const float *gw[3], *gas[3], *gad[3], *gbp[3], *fw[3], *fbp[3], *fgp[3], *fbt[3];
    for (int l = 0; l < 3; l++) {
        int b = 3 + 8 * l;
        gw[l]  = (const float*)d_in[b + 0];
        gas[l] = (const float*)d_in[b + 1];
        gad[l] = (const float*)d_in[b + 2];
        gbp[l] = (const float*)d_in[b + 3];
        fw[l]  = (const float*)d_in[b + 4];
        fbp[l] = (const float*)d_in[b + 5];
        fgp[l] = (const float*)d_in[b + 6];
        fbt[l] = (const float*)d_in[b + 7];
    }
    const float* cw = (const float*)d_in[27];
    const float* cb = (const float*)d_in[28];

    char* p = (char*)d_ws;
    auto carve = [&](size_t bytes) -> char* {
        char* r = p; p += (bytes + 255) & ~(size_t)255; return r;
    };
    float* xA   = (float*)carve((size_t)N * HD * 4);
    float* xB   = (float*)carve((size_t)N * HD * 4);
    unsigned short* hbuf = (unsigned short*)carve((size_t)N * HD * 2);   // bf16 h
    float* als  = (float*)carve((size_t)N * 4 * 4);
    float* ald  = (float*)carve((size_t)N * 4 * 4);
    int* rp   = (int*)carve((size_t)(N + 1) * 4);
    int* deg  = (int*)carve((size_t)N * 4);
    int* cur  = (int*)carve((size_t)N * 4);
    int* bsum = (int*)carve(4096);
    int* col  = (int*)carve((size_t)Etot * 4);
    unsigned short* wT[3];
    for (int l = 0; l < 3; l++) {
        int K = (l == 0) ? 512 : HD;
        wT[l] = (unsigned short*)carve((size_t)256 * K * 2);
    }

    // ---- weight cast+transpose+concat (tiny) ----
    for (int l = 0; l < 3; l++) {
        int K = (l == 0) ? 512 : HD;
        int nt = K * 256;
        prep_w2<<<(nt + 255) / 256, 256, 0, stream>>>(gw[l], fw[l], wT[l], K);
    }

    // ---- CSR by dst ----
    hipMemsetAsync(deg, 0, (size_t)N * 4, stream);
    hist_kernel<<<(Etot + 255) / 256, 256, 0, stream>>>(ei, E, N, deg);
    int nb = (N + 1023) / 1024;
    scan1<<<nb, 256, 0, stream>>>(deg, rp, bsum, N);
    scan2<<<1, 64, 0, stream>>>(bsum, nb);
    scan3<<<(N + 256) / 256, 256, 0, stream>>>(rp, cur, bsum, N, Etot);
    scatter_kernel<<<(Etot + 255) / 256, 256, 0, stream>>>(ei, E, N, cur, col);

    // ---- 3 message-passing layers (al fused into gemm; cls fused into
    //      last agg) ----
    for (int l = 0; l < 3; l++) {
        const float* xin = (l == 0) ? x0 : ((l == 1) ? xA : xB);
        float* xout = (l == 1) ? xB : xA;
        int K = (l == 0) ? 512 : HD;
        int mblocks = (N + 127) / 128;
        gemm_dual<<<mblocks, 512, 0, stream>>>(xin, wT[l], hbuf, xout, N, K,
                                               fbp[l], fgp[l], fbt[l], gbp[l],
                                               gas[l], gad[l], als, ald);
        agg_kernel<<<(N + 3) / 4, 256, 0, stream>>>(
            hbuf, als, ald, rp, col, xout, N,
            (l == 2) ? cw : nullptr, cb, (float*)d_out);
    }
}